// Round 1
// baseline (784.738 us; speedup 1.0000x reference)
//
#include <hip/hip_runtime.h>
#include <hip/hip_bf16.h>

#define NEG_SLOPE 0.2f

__device__ __forceinline__ float wave_red_sum(float v) {
    for (int o = 32; o > 0; o >>= 1) v += __shfl_xor(v, o, 64);
    return v;
}
__device__ __forceinline__ float wave_red_max(float v) {
    for (int o = 32; o > 0; o >>= 1) v = fmaxf(v, __shfl_xor(v, o, 64));
    return v;
}

// x[r] = relu(dot64(z, fc_w[r]) + fc_b[r]); 16 lanes per row, float4 loads (coalesced 256B/row)
__global__ void fc_kernel(const float* __restrict__ z, const float* __restrict__ fcw,
                          const float* __restrict__ fcb, float* __restrict__ x, int R) {
    int t = blockIdx.x * 256 + threadIdx.x;
    int r = t >> 4;
    int j = t & 15;
    if (r >= R) return;
    float4 wz = ((const float4*)z)[j];
    float4 ww = ((const float4*)fcw)[r * 16 + j];
    float p = wz.x * ww.x + wz.y * ww.y + wz.z * ww.z + wz.w * ww.w;
    p += __shfl_xor(p, 1, 64);
    p += __shfl_xor(p, 2, 64);
    p += __shfl_xor(p, 4, 64);
    p += __shfl_xor(p, 8, 64);
    if (j == 0) {
        float v = p + fcb[r];
        x[r] = v > 0.f ? v : 0.f;
    }
}

// h = x @ W.T  (W row-major [FOUT][FIN]); block=256, LDS-swizzled W chunk, broadcast x reads.
template <int FIN, int FOUT, int NV>
__global__ void gemm_kernel(const float* __restrict__ x, const float* __restrict__ W,
                            float* __restrict__ h) {
    constexpr int KC = 64;
    constexpr int VG = 256 / FOUT;     // vgroups per block
    constexpr int NPB = VG * NV;       // nodes per block
    __shared__ float Ws[FOUT * KC];    // swizzled: Ws[f*KC + (kk+f)%KC]
    __shared__ float xs[NPB * FIN];    // plain (reads are wave-uniform broadcasts)
    const int tid = threadIdx.x;
    const int f = tid % FOUT;
    const int vg = tid / FOUT;
    const int v0 = blockIdx.x * NPB;

    for (int i = tid; i < NPB * FIN; i += 256) xs[i] = x[v0 * FIN + i];

    float acc[NV];
#pragma unroll
    for (int j = 0; j < NV; j++) acc[j] = 0.f;

    for (int c0 = 0; c0 < FIN; c0 += KC) {
        __syncthreads();
        for (int i = tid; i < FOUT * KC; i += 256) {
            int ff = i / KC, kk = i % KC;
            Ws[ff * KC + ((kk + ff) & (KC - 1))] = W[ff * FIN + c0 + kk];
        }
        __syncthreads();
#pragma unroll 4
        for (int kk = 0; kk < KC; kk++) {
            float w = Ws[f * KC + ((kk + f) & (KC - 1))];
#pragma unroll
            for (int j = 0; j < NV; j++)
                acc[j] += w * xs[(vg * NV + j) * FIN + c0 + kk];
        }
    }
#pragma unroll
    for (int j = 0; j < NV; j++) {
        int v = vg * NV + j;
        h[(v0 + v) * FOUT + f] = acc[j];
    }
}

// hs[v] = h[v,:].a_s ; hd[v] = h[v,:].a_d  — one wave per node
template <int FOUT>
__global__ void att_kernel(const float* __restrict__ h, const float* __restrict__ as,
                           const float* __restrict__ ad, float* __restrict__ hs,
                           float* __restrict__ hd, int N) {
    int wave = threadIdx.x >> 6;
    int lane = threadIdx.x & 63;
    int v = blockIdx.x * 4 + wave;
    if (v >= N) return;
    float ps = 0.f, pd = 0.f;
#pragma unroll
    for (int f = lane; f < FOUT; f += 64) {
        float hv = h[v * FOUT + f];
        ps += hv * as[f];
        pd += hv * ad[f];
    }
    ps = wave_red_sum(ps);
    pd = wave_red_sum(pd);
    if (lane == 0) { hs[v] = ps; hd[v] = pd; }
}

// ---- CSR build (dst-sorted) ----
__global__ void hist_kernel(const int* __restrict__ dst, int* __restrict__ cnt, int E) {
    int e = blockIdx.x * 256 + threadIdx.x;
    if (e < E) atomicAdd(&cnt[dst[e]], 1);
}

__global__ void scan1_kernel(const int* __restrict__ cnt, int* __restrict__ rowtmp,
                             int* __restrict__ bsum) {
    __shared__ int sd[256];
    int i = blockIdx.x * 256 + threadIdx.x;
    sd[threadIdx.x] = cnt[i];
    for (int off = 1; off < 256; off <<= 1) {
        __syncthreads();
        int t = (threadIdx.x >= off) ? sd[threadIdx.x - off] : 0;
        __syncthreads();
        sd[threadIdx.x] += t;
    }
    __syncthreads();
    rowtmp[i] = sd[threadIdx.x];
    if (threadIdx.x == 255) bsum[blockIdx.x] = sd[255];
}

__global__ void scan2_kernel(const int* __restrict__ bsum, int* __restrict__ boff, int nb) {
    __shared__ int sd[128];
    int i = threadIdx.x;
    int orig = (i < nb) ? bsum[i] : 0;
    sd[i] = orig;
    for (int off = 1; off < 128; off <<= 1) {
        __syncthreads();
        int t = (i >= off) ? sd[i - off] : 0;
        __syncthreads();
        sd[i] += t;
    }
    __syncthreads();
    if (i < nb) boff[i] = sd[i] - orig;  // exclusive = inclusive - self
}

__global__ void scan3_kernel(const int* __restrict__ cnt, const int* __restrict__ rowtmp,
                             const int* __restrict__ boff, int* __restrict__ rowptr,
                             int* __restrict__ cursor, int N) {
    int i = blockIdx.x * 256 + threadIdx.x;
    if (i > N) return;
    int b = i >> 8;
    int excl = boff[b] + rowtmp[i] - cnt[i];
    rowptr[i] = excl;
    if (i < N) cursor[i] = excl;
}

__global__ void scatter_kernel(const int* __restrict__ src, const int* __restrict__ dst,
                               int* __restrict__ cursor, int* __restrict__ col, int E) {
    int e = blockIdx.x * 256 + threadIdx.x;
    if (e < E) {
        int p = atomicAdd(&cursor[dst[e]], 1);
        col[p] = src[e];
    }
}

// softmax-weighted aggregation over incoming edges; one wave per dst node
template <int FOUT, bool RELU>
__global__ void agg_kernel(const float* __restrict__ h, const float* __restrict__ hs,
                           const float* __restrict__ hd, const int* __restrict__ rowptr,
                           const int* __restrict__ col, const float* __restrict__ b,
                           float* __restrict__ out) {
    const int v = blockIdx.x;
    const int lane = threadIdx.x;  // blockDim = 64
    const int s0 = rowptr[v], s1 = rowptr[v + 1];
    if (s1 == s0) {  // empty segment: out = 0 + b (matches jax: 0/(0+1e-16)=0)
        float bv = b[lane];
        if (RELU) bv = bv > 0.f ? bv : 0.f;
        out[v * FOUT + lane] = bv;
        if (FOUT == 128) {
            float b2 = b[lane + 64];
            if (RELU) b2 = b2 > 0.f ? b2 : 0.f;
            out[v * FOUT + 64 + lane] = b2;
        }
        return;
    }
    const float hdv = hd[v];
    float m = -1e30f;
    for (int base = s0; base < s1; base += 64) {
        int j = base + lane;
        if (j < s1) {
            float e = hs[col[j]] + hdv;
            e = e > 0.f ? e : NEG_SLOPE * e;
            m = fmaxf(m, e);
        }
    }
    m = wave_red_max(m);
    float ssum = 0.f;
    for (int base = s0; base < s1; base += 64) {
        int j = base + lane;
        if (j < s1) {
            float e = hs[col[j]] + hdv;
            e = e > 0.f ? e : NEG_SLOPE * e;
            ssum += __expf(e - m);
        }
    }
    ssum = wave_red_sum(ssum);
    float acc0 = 0.f, acc1 = 0.f;
    for (int base = s0; base < s1; base += 64) {
        int j = base + lane;
        int sv = 0;
        float w = 0.f;
        if (j < s1) {
            sv = col[j];
            float e = hs[sv] + hdv;
            e = e > 0.f ? e : NEG_SLOPE * e;
            w = __expf(e - m);
        }
        int cnt = min(64, s1 - base);
        for (int jj = 0; jj < cnt; jj++) {
            float wj = __shfl(w, jj, 64);
            int svj = __shfl(sv, jj, 64);
            acc0 += wj * h[svj * FOUT + lane];
            if (FOUT == 128) acc1 += wj * h[svj * FOUT + 64 + lane];
        }
    }
    float inv = 1.f / (ssum + 1e-16f);
    float o0 = acc0 * inv + b[lane];
    if (RELU) o0 = o0 > 0.f ? o0 : 0.f;
    out[v * FOUT + lane] = o0;
    if (FOUT == 128) {
        float o1 = acc1 * inv + b[lane + 64];
        if (RELU) o1 = o1 > 0.f ? o1 : 0.f;
        out[v * FOUT + 64 + lane] = o1;
    }
}

extern "C" void kernel_launch(void* const* d_in, const int* in_sizes, int n_in,
                              void* d_out, int out_size, void* d_ws, size_t ws_size,
                              hipStream_t stream) {
    const float* z   = (const float*)d_in[0];
    const int*   ei  = (const int*)d_in[1];
    const float* fcw = (const float*)d_in[2];
    const float* fcb = (const float*)d_in[3];
    const float* W0  = (const float*)d_in[4];
    const float* as0 = (const float*)d_in[5];
    const float* ad0 = (const float*)d_in[6];
    const float* b0  = (const float*)d_in[7];
    const float* W1  = (const float*)d_in[8];
    const float* as1 = (const float*)d_in[9];
    const float* ad1 = (const float*)d_in[10];
    const float* b1  = (const float*)d_in[11];
    const float* W2  = (const float*)d_in[12];
    const float* as2 = (const float*)d_in[13];
    const float* ad2 = (const float*)d_in[14];
    const float* b2  = (const float*)d_in[15];

    const int E = in_sizes[1] / 2;       // 640000
    const int R = in_sizes[3];           // N*64 = 1280000
    const int N = R / 64;                // 20000
    const int* src = ei;
    const int* dst = ei + E;

    // workspace layout (~29 MB)
    float* xbuf = (float*)d_ws;                 // N*64
    float* hbuf = xbuf + (size_t)N * 64;        // N*128
    float* obuf = hbuf + (size_t)N * 128;       // N*128
    float* hs   = obuf + (size_t)N * 128;       // N
    float* hd   = hs + N;                       // N
    int* cnt    = (int*)(hd + N);               // 20480 (padded, zeroed)
    int* rowtmp = cnt + 20480;                  // 20480
    int* rowptr = rowtmp + 20480;               // 20032
    int* cursor = rowptr + 20032;               // 20000
    int* bsum   = cursor + 20000;               // 128
    int* boff   = bsum + 128;                   // 128
    int* col    = boff + 128;                   // E

    // CSR build (dst-sorted edge list)
    hipMemsetAsync(cnt, 0, 20480 * sizeof(int), stream);
    hist_kernel<<<(E + 255) / 256, 256, 0, stream>>>(dst, cnt, E);
    scan1_kernel<<<80, 256, 0, stream>>>(cnt, rowtmp, bsum);
    scan2_kernel<<<1, 128, 0, stream>>>(bsum, boff, 80);
    scan3_kernel<<<79, 256, 0, stream>>>(cnt, rowtmp, boff, rowptr, cursor, N);
    scatter_kernel<<<(E + 255) / 256, 256, 0, stream>>>(src, dst, cursor, col, E);

    // fc: z -> x [N,64]
    fc_kernel<<<R / 16, 256, 0, stream>>>(z, fcw, fcb, xbuf, R);

    // Layer 0: [N,64] -> [N,128], relu
    gemm_kernel<64, 128, 8><<<N / 16, 256, 0, stream>>>(xbuf, W0, hbuf);
    att_kernel<128><<<N / 4, 256, 0, stream>>>(hbuf, as0, ad0, hs, hd, N);
    agg_kernel<128, true><<<N, 64, 0, stream>>>(hbuf, hs, hd, rowptr, col, b0, obuf);

    // Layer 1: [N,128] -> [N,128], relu
    gemm_kernel<128, 128, 8><<<N / 16, 256, 0, stream>>>(obuf, W1, hbuf);
    att_kernel<128><<<N / 4, 256, 0, stream>>>(hbuf, as1, ad1, hs, hd, N);
    agg_kernel<128, true><<<N, 64, 0, stream>>>(hbuf, hs, hd, rowptr, col, b1, obuf);

    // Layer 2: [N,128] -> [N,64], no relu, -> d_out
    gemm_kernel<128, 64, 8><<<N / 32, 256, 0, stream>>>(obuf, W2, hbuf);
    att_kernel<64><<<N / 4, 256, 0, stream>>>(hbuf, as2, ad2, hs, hd, N);
    agg_kernel<64, false><<<N, 64, 0, stream>>>(hbuf, hs, hd, rowptr, col, b2, (float*)d_out);
}

// Round 2
// 669.990 us; speedup vs baseline: 1.1713x; 1.1713x over previous
//
#include <hip/hip_runtime.h>

#define NEG_SLOPE 0.2f

typedef __attribute__((ext_vector_type(8))) short short8;
typedef __attribute__((ext_vector_type(4))) float v4f;

__device__ __forceinline__ float wave_red_sum(float v) {
    for (int o = 32; o > 0; o >>= 1) v += __shfl_xor(v, o, 64);
    return v;
}
__device__ __forceinline__ float wave_red_max(float v) {
    for (int o = 32; o > 0; o >>= 1) v = fmaxf(v, __shfl_xor(v, o, 64));
    return v;
}
__device__ __forceinline__ unsigned short f2bf(float f) {
    union { float f; unsigned int u; } x; x.f = f;
    unsigned int r = x.u + 0x7fffu + ((x.u >> 16) & 1u);
    return (unsigned short)(r >> 16);
}
__device__ __forceinline__ float bf2f(unsigned short b) {
    union { unsigned int u; float f; } x; x.u = ((unsigned int)b) << 16;
    return x.f;
}
__device__ __forceinline__ void split_bf(float v, unsigned short& hi, unsigned short& lo) {
    hi = f2bf(v);
    lo = f2bf(v - bf2f(hi));
}

// x[r] = relu(dot64(z, fc_w[r]) + fc_b[r]) -> bf16 hi/lo split. 16 lanes/row, float4 loads.
__global__ void fc_kernel(const float* __restrict__ z, const float* __restrict__ fcw,
                          const float* __restrict__ fcb, unsigned short* __restrict__ xhi,
                          unsigned short* __restrict__ xlo, int R) {
    int t = blockIdx.x * 256 + threadIdx.x;
    int r = t >> 4;
    int j = t & 15;
    if (r >= R) return;
    float4 wz = ((const float4*)z)[j];
    float4 ww = ((const float4*)fcw)[r * 16 + j];
    float p = wz.x * ww.x + wz.y * ww.y + wz.z * ww.z + wz.w * ww.w;
    p += __shfl_xor(p, 1, 64);
    p += __shfl_xor(p, 2, 64);
    p += __shfl_xor(p, 4, 64);
    p += __shfl_xor(p, 8, 64);
    if (j == 0) {
        float v = p + fcb[r];
        v = v > 0.f ? v : 0.f;
        unsigned short hi, lo;
        split_bf(v, hi, lo);
        xhi[r] = hi;
        xlo[r] = lo;
    }
}

// Split the three W matrices (fp32 [FOUT][FIN]) into bf16 hi/lo, concatenated.
__global__ void wsplit_kernel(const float* __restrict__ W0, const float* __restrict__ W1,
                              const float* __restrict__ W2, int n0, int n1, int n2,
                              unsigned short* __restrict__ whi, unsigned short* __restrict__ wlo) {
    int i = blockIdx.x * 256 + threadIdx.x;
    if (i >= n0 + n1 + n2) return;
    float v;
    if (i < n0) v = W0[i];
    else if (i < n0 + n1) v = W1[i - n0];
    else v = W2[i - n0 - n1];
    unsigned short hi, lo;
    split_bf(v, hi, lo);
    whi[i] = hi;
    wlo[i] = lo;
}

// h = x @ W.T via bf16-split MFMA (3 mfma per tile: hh + hl + lh), fragments straight
// from global (x L3-resident, W L2-resident). Fused att: hs = h.as, hd = h.ad computed
// from the accumulators (16-lane reduce), no extra h pass.
// A-frag: A[m=lane&15][k=quad*8+j]; B-frag: B[k=quad*8+j][n=lane&15] = W[n][k];
// C/D: col=lane&15 (f), row=quad*4+reg (node).
template <int FIN, int FOUT>
__global__ __launch_bounds__(256) void gemm_att_kernel(
        const unsigned short* __restrict__ xhi, const unsigned short* __restrict__ xlo,
        const unsigned short* __restrict__ whi, const unsigned short* __restrict__ wlo,
        const float* __restrict__ as, const float* __restrict__ ad,
        float* __restrict__ h, float* __restrict__ hs, float* __restrict__ hd, int Mtiles) {
    constexpr int NT = FOUT / 16;
    constexpr int KS = FIN / 32;
    const int wid = blockIdx.x * 4 + (threadIdx.x >> 6);
    if (wid >= Mtiles) return;
    const int lane = threadIdx.x & 63;
    const int l15 = lane & 15;
    const int quad = lane >> 4;
    const int v0 = wid * 16;

    v4f acc[NT];
#pragma unroll
    for (int nt = 0; nt < NT; nt++) acc[nt] = (v4f){0.f, 0.f, 0.f, 0.f};

    const unsigned short* xh = xhi + (v0 + l15) * FIN + quad * 8;
    const unsigned short* xl = xlo + (v0 + l15) * FIN + quad * 8;
    const unsigned short* wh = whi + l15 * FIN + quad * 8;
    const unsigned short* wl = wlo + l15 * FIN + quad * 8;
#pragma unroll
    for (int ks = 0; ks < KS; ks++) {
        short8 ah = *(const short8*)(xh + ks * 32);
        short8 al = *(const short8*)(xl + ks * 32);
#pragma unroll
        for (int nt = 0; nt < NT; nt++) {
            short8 bh = *(const short8*)(wh + nt * 16 * FIN + ks * 32);
            short8 bl = *(const short8*)(wl + nt * 16 * FIN + ks * 32);
            acc[nt] = __builtin_amdgcn_mfma_f32_16x16x32_bf16(ah, bh, acc[nt], 0, 0, 0);
            acc[nt] = __builtin_amdgcn_mfma_f32_16x16x32_bf16(ah, bl, acc[nt], 0, 0, 0);
            acc[nt] = __builtin_amdgcn_mfma_f32_16x16x32_bf16(al, bh, acc[nt], 0, 0, 0);
        }
    }
    float ps[4] = {0.f, 0.f, 0.f, 0.f}, pd[4] = {0.f, 0.f, 0.f, 0.f};
#pragma unroll
    for (int nt = 0; nt < NT; nt++) {
        float av = as[nt * 16 + l15];
        float dv = ad[nt * 16 + l15];
#pragma unroll
        for (int r = 0; r < 4; r++) {
            float c = acc[nt][r];
            h[(v0 + quad * 4 + r) * FOUT + nt * 16 + l15] = c;
            ps[r] += c * av;
            pd[r] += c * dv;
        }
    }
#pragma unroll
    for (int o = 8; o >= 1; o >>= 1) {
#pragma unroll
        for (int r = 0; r < 4; r++) {
            ps[r] += __shfl_xor(ps[r], o, 64);
            pd[r] += __shfl_xor(pd[r], o, 64);
        }
    }
    if (l15 == 0) {
#pragma unroll
        for (int r = 0; r < 4; r++) {
            hs[v0 + quad * 4 + r] = ps[r];
            hd[v0 + quad * 4 + r] = pd[r];
        }
    }
}

// ---- CSR build (dst-sorted) ----
__global__ void hist_kernel(const int* __restrict__ dst, int* __restrict__ cnt, int E) {
    int e = blockIdx.x * 256 + threadIdx.x;
    if (e < E) atomicAdd(&cnt[dst[e]], 1);
}

__global__ void scan1_kernel(const int* __restrict__ cnt, int* __restrict__ rowtmp,
                             int* __restrict__ bsum) {
    __shared__ int sd[256];
    int i = blockIdx.x * 256 + threadIdx.x;
    sd[threadIdx.x] = cnt[i];
    for (int off = 1; off < 256; off <<= 1) {
        __syncthreads();
        int t = (threadIdx.x >= off) ? sd[threadIdx.x - off] : 0;
        __syncthreads();
        sd[threadIdx.x] += t;
    }
    __syncthreads();
    rowtmp[i] = sd[threadIdx.x];
    if (threadIdx.x == 255) bsum[blockIdx.x] = sd[255];
}

__global__ void scan2_kernel(const int* __restrict__ bsum, int* __restrict__ boff, int nb) {
    __shared__ int sd[128];
    int i = threadIdx.x;
    int orig = (i < nb) ? bsum[i] : 0;
    sd[i] = orig;
    for (int off = 1; off < 128; off <<= 1) {
        __syncthreads();
        int t = (i >= off) ? sd[i - off] : 0;
        __syncthreads();
        sd[i] += t;
    }
    __syncthreads();
    if (i < nb) boff[i] = sd[i] - orig;
}

__global__ void scan3_kernel(const int* __restrict__ cnt, const int* __restrict__ rowtmp,
                             const int* __restrict__ boff, int* __restrict__ rowptr,
                             int* __restrict__ cursor, int N) {
    int i = blockIdx.x * 256 + threadIdx.x;
    if (i > N) return;
    int b = i >> 8;
    int excl = boff[b] + rowtmp[i] - cnt[i];
    rowptr[i] = excl;
    if (i < N) cursor[i] = excl;
}

__global__ void scatter_kernel(const int* __restrict__ src, const int* __restrict__ dst,
                               int* __restrict__ cursor, int* __restrict__ col, int E) {
    int e = blockIdx.x * 256 + threadIdx.x;
    if (e < E) {
        int p = atomicAdd(&cursor[dst[e]], 1);
        col[p] = src[e];
    }
}

// Softmax-weighted aggregation; one wave per node, 4 nodes/block, no barriers.
// Per-edge (sv, w) cached once in LDS; phase C does unroll-4 independent coalesced gathers.
template <int FOUT, bool RELU, bool SPLIT>
__global__ __launch_bounds__(256) void agg_kernel(
        const float* __restrict__ h, const float* __restrict__ hs, const float* __restrict__ hd,
        const int* __restrict__ rowptr, const int* __restrict__ col, const float* __restrict__ b,
        float* __restrict__ out, unsigned short* __restrict__ ohi,
        unsigned short* __restrict__ olo) {
    constexpr int FPT = FOUT / 64;  // features per thread (1 or 2)
    constexpr int CAP = 512;        // per-node LDS edge cache (deg ~Poisson(32); tail path covers overflow)
    __shared__ float sw[4][CAP];
    __shared__ int ssv[4][CAP];
    const int w = threadIdx.x >> 6;
    const int lane = threadIdx.x & 63;
    const int v = blockIdx.x * 4 + w;
    float* swv = sw[w];
    int* ssvv = ssv[w];
    const int s0 = rowptr[v];
    const int deg = rowptr[v + 1] - s0;
    float acc[FPT];
#pragma unroll
    for (int i = 0; i < FPT; i++) acc[i] = 0.f;
    float inv = 0.f;
    if (deg > 0) {
        const float hdv = hd[v];
        float mt = -1e30f;
        for (int j = lane; j < deg; j += 64) {
            int sv = col[s0 + j];
            float e = hs[sv] + hdv;
            e = e > 0.f ? e : NEG_SLOPE * e;
            if (j < CAP) { ssvv[j] = sv; swv[j] = e; }
            mt = fmaxf(mt, e);
        }
        const float m = wave_red_max(mt);
        float st = 0.f;
        for (int j = lane; j < deg; j += 64) {
            float e;
            if (j < CAP) e = swv[j];
            else {
                int sv = col[s0 + j];
                e = hs[sv] + hdv;
                e = e > 0.f ? e : NEG_SLOPE * e;
            }
            float ww = __expf(e - m);
            if (j < CAP) swv[j] = ww;
            st += ww;
        }
        const float ssum = wave_red_sum(st);
        inv = 1.f / (ssum + 1e-16f);
        const int dmain = deg < CAP ? deg : CAP;
#pragma unroll 4
        for (int jj = 0; jj < dmain; jj++) {
            float ww = swv[jj];
            int sv = ssvv[jj];
            if (FPT == 2) {
                float2 hv = ((const float2*)(h + sv * FOUT))[lane];
                acc[0] += ww * hv.x;
                acc[1] += ww * hv.y;
            } else {
                acc[0] += ww * h[sv * FOUT + lane];
            }
        }
        for (int jj = CAP; jj < deg; jj++) {  // cold overflow path
            int sv = col[s0 + jj];
            float e = hs[sv] + hdv;
            e = e > 0.f ? e : NEG_SLOPE * e;
            float ww = __expf(e - m);
            if (FPT == 2) {
                float2 hv = ((const float2*)(h + sv * FOUT))[lane];
                acc[0] += ww * hv.x;
                acc[1] += ww * hv.y;
            } else {
                acc[0] += ww * h[sv * FOUT + lane];
            }
        }
    }
    float o[FPT];
#pragma unroll
    for (int i = 0; i < FPT; i++) {
        float bv = b[lane * FPT + i];
        o[i] = acc[i] * inv + bv;  // deg==0: 0*0 + b, matches jax
        if (RELU) o[i] = fmaxf(o[i], 0.f);
    }
    if (SPLIT) {
        if (FPT == 2) {
            unsigned short h0, l0, h1, l1;
            split_bf(o[0], h0, l0);
            split_bf(o[1], h1, l1);
            ((ushort2*)ohi)[v * 64 + lane] = make_ushort2(h0, h1);
            ((ushort2*)olo)[v * 64 + lane] = make_ushort2(l0, l1);
        } else {
            unsigned short hb, lb;
            split_bf(o[0], hb, lb);
            ohi[v * FOUT + lane] = hb;
            olo[v * FOUT + lane] = lb;
        }
    } else {
        if (FPT == 2)
            ((float2*)out)[v * 64 + lane] = make_float2(o[0], o[1]);
        else
            out[v * FOUT + lane] = o[0];
    }
}

extern "C" void kernel_launch(void* const* d_in, const int* in_sizes, int n_in,
                              void* d_out, int out_size, void* d_ws, size_t ws_size,
                              hipStream_t stream) {
    const float* z   = (const float*)d_in[0];
    const int*   ei  = (const int*)d_in[1];
    const float* fcw = (const float*)d_in[2];
    const float* fcb = (const float*)d_in[3];
    const float* W0  = (const float*)d_in[4];
    const float* as0 = (const float*)d_in[5];
    const float* ad0 = (const float*)d_in[6];
    const float* b0  = (const float*)d_in[7];
    const float* W1  = (const float*)d_in[8];
    const float* as1 = (const float*)d_in[9];
    const float* ad1 = (const float*)d_in[10];
    const float* b1  = (const float*)d_in[11];
    const float* W2  = (const float*)d_in[12];
    const float* as2 = (const float*)d_in[13];
    const float* ad2 = (const float*)d_in[14];
    const float* b2  = (const float*)d_in[15];

    const int E = in_sizes[1] / 2;   // 640000
    const int R = in_sizes[3];       // N*64
    const int N = R / 64;            // 20000
    const int n0 = in_sizes[4];      // 128*64
    const int n1 = in_sizes[8];      // 128*128
    const int n2 = in_sizes[12];     // 64*128
    const int* src = ei;
    const int* dst = ei + E;

    // workspace carve (256B-aligned)
    char* p = (char*)d_ws;
    auto carve = [&](size_t bytes) {
        void* r = (void*)p;
        p += (bytes + 255) & ~(size_t)255;
        return r;
    };
    unsigned short* xhi = (unsigned short*)carve((size_t)N * 128 * 2);
    unsigned short* xlo = (unsigned short*)carve((size_t)N * 128 * 2);
    float* hbuf = (float*)carve((size_t)N * 128 * 4);
    float* hs = (float*)carve((size_t)N * 4);
    float* hd = (float*)carve((size_t)N * 4);
    unsigned short* whi = (unsigned short*)carve((size_t)(n0 + n1 + n2) * 2);
    unsigned short* wlo = (unsigned short*)carve((size_t)(n0 + n1 + n2) * 2);
    const int nb = (N + 255) / 256;          // scan blocks (79)
    int* cnt = (int*)carve((size_t)nb * 256 * 4);
    int* rowtmp = (int*)carve((size_t)nb * 256 * 4);
    int* rowptr = (int*)carve((size_t)(N + 32) * 4);
    int* cursor = (int*)carve((size_t)N * 4);
    int* bsum = (int*)carve(128 * 4);
    int* boff = (int*)carve(128 * 4);
    int* col = (int*)carve((size_t)E * 4);

    // CSR build (dst-sorted edge list)
    hipMemsetAsync(cnt, 0, (size_t)nb * 256 * 4, stream);
    hist_kernel<<<(E + 255) / 256, 256, 0, stream>>>(dst, cnt, E);
    scan1_kernel<<<nb, 256, 0, stream>>>(cnt, rowtmp, bsum);
    scan2_kernel<<<1, 128, 0, stream>>>(bsum, boff, nb);
    scan3_kernel<<<(N + 256) / 256, 256, 0, stream>>>(cnt, rowtmp, boff, rowptr, cursor, N);
    scatter_kernel<<<(E + 255) / 256, 256, 0, stream>>>(src, dst, cursor, col, E);

    // weight split + fc
    wsplit_kernel<<<(n0 + n1 + n2 + 255) / 256, 256, 0, stream>>>(W0, W1, W2, n0, n1, n2, whi, wlo);
    fc_kernel<<<R / 16, 256, 0, stream>>>(z, fcw, fcb, xhi, xlo, R);

    const int Mtiles = N / 16;          // 1250
    const int gblocks = (Mtiles + 3) / 4;

    // Layer 0: [N,64] -> [N,128], relu
    gemm_att_kernel<64, 128><<<gblocks, 256, 0, stream>>>(xhi, xlo, whi, wlo, as0, ad0,
                                                          hbuf, hs, hd, Mtiles);
    agg_kernel<128, true, true><<<N / 4, 256, 0, stream>>>(hbuf, hs, hd, rowptr, col, b0,
                                                           nullptr, xhi, xlo);
    // Layer 1: [N,128] -> [N,128], relu
    gemm_att_kernel<128, 128><<<gblocks, 256, 0, stream>>>(xhi, xlo, whi + n0, wlo + n0, as1, ad1,
                                                           hbuf, hs, hd, Mtiles);
    agg_kernel<128, true, true><<<N / 4, 256, 0, stream>>>(hbuf, hs, hd, rowptr, col, b1,
                                                           nullptr, xhi, xlo);
    // Layer 2: [N,128] -> [N,64], no relu
    gemm_att_kernel<128, 64><<<gblocks, 256, 0, stream>>>(xhi, xlo, whi + n0 + n1, wlo + n0 + n1,
                                                          as2, ad2, hbuf, hs, hd, Mtiles);
    agg_kernel<64, false, false><<<N / 4, 256, 0, stream>>>(hbuf, hs, hd, rowptr, col, b2,
                                                            (float*)d_out, nullptr, nullptr);
}